// Round 17
// baseline (71.910 us; speedup 1.0000x reference)
//
#include <hip/hip_runtime.h>
#include <math.h>

typedef __attribute__((ext_vector_type(8))) short bf16x8;
typedef __attribute__((ext_vector_type(4))) float f32x4;
typedef unsigned short ushort_t;

#define GN 8192
#define NGRP 1024
#define DDIM 128
#define NCH 16
#define LOG2E 1.4426950408889634f
#define LN2 0.6931471805599453f

#if __has_builtin(__builtin_amdgcn_exp2f)
#define EXP2F(x) __builtin_amdgcn_exp2f(x)
#else
#define EXP2F(x) exp2f(x)
#endif
#if __has_builtin(__builtin_amdgcn_logf)
#define LOG2FAST(x) __builtin_amdgcn_logf(x)
#else
#define LOG2FAST(x) log2f(x)
#endif

// float offsets in wf (wf = ws + 4MB bf16 region)
#define ROWST 0                          // [8192][16][2] pass0 row partials (E, L)
#define GRPB  (ROWST + GN*NCH*2)         // [1024][16]    pass0 group sB partials
#define DT    (GRPB + NGRP*NCH)          // [2][8192]     diag-block row/col sumexp
#define DU8   (DT + 2*GN)                // [1024]        diag 8x8 block sumexp (shared)
#define GSUM  (DU8 + NGRP)               // [2][1024][128] per-group column sums
#define CSUMP (GSUM + 2*NGRP*DDIM)       // [2][32][128]  column-sum partials
#define COLP  (CSUMP + 2*32*DDIM)        // [128][8192][2] pass1 col partials (E, L)
#define GRP2P (COLP + 128*GN*2)          // [128][1024]   pass1 col-group sB partials
#define FIN2  (GRP2P + 128*NGRP)         // [8192][2]     reduced pass1 (E, L)
#define SB2   (FIN2 + GN*2)              // [1024]        reduced pass1 group sB
#define PART  (SB2 + NGRP)               // [64] loss partials

__device__ __forceinline__ ushort_t f2bf(float x) {
  unsigned u = __float_as_uint(x);
  unsigned r = (u + 0x7fffu + ((u >> 16) & 1u)) >> 16;
  return (ushort_t)r;
}
__device__ __forceinline__ float bf2f(unsigned h) {
  return __uint_as_float(h << 16);
}

// DPP helpers. row_shr chains: octet sums valid on lanes li=7 / li=15.
__device__ __forceinline__ float dpp_shr1_add(float v) {
  int s = __builtin_amdgcn_update_dpp(0, __float_as_int(v), 0x111, 0xF, 0xF, true);
  return v + __int_as_float(s);
}
__device__ __forceinline__ float dpp_shr2_add(float v) {
  int s = __builtin_amdgcn_update_dpp(0, __float_as_int(v), 0x112, 0xF, 0xF, true);
  return v + __int_as_float(s);
}
__device__ __forceinline__ float dpp_shr4_add(float v) {
  int s = __builtin_amdgcn_update_dpp(0, __float_as_int(v), 0x114, 0xF, 0xF, true);
  return v + __int_as_float(s);
}
// row_ror:8 = lane l <-> l^8 within each 16-lane row
__device__ __forceinline__ float dpp_ror8_add(float v) {
  int s = __builtin_amdgcn_update_dpp(0, __float_as_int(v), 0x128, 0xF, 0xF, true);
  return v + __int_as_float(s);
}

// One block per (matrix m, group g): normalize 8 rows, store bf16, emit
// per-group column sums of the bf16-rounded values.
__global__ __launch_bounds__(256) void normg_kernel(
    const float* __restrict__ f1, const float* __restrict__ f2,
    const float* __restrict__ scp, ushort_t* __restrict__ wsu,
    float* __restrict__ wf) {
  const int b = blockIdx.x;            // m*1024 + g
  const int m = b >> 10;
  const int g = b & 1023;
  const int t = threadIdx.x;
  const int r = t >> 5;
  const int c4 = t & 31;
  const float* __restrict__ f = m ? f2 : f1;
  const float fac0 = m ? 1.0f : (scp[0] * LOG2E);

  const float4 v = ((const float4*)(f + ((size_t)(g * 8 + r)) * DDIM))[c4];
  float ss = v.x * v.x + v.y * v.y + v.z * v.z + v.w * v.w;
  #pragma unroll
  for (int d = 1; d < 32; d <<= 1) ss += __shfl_xor(ss, d);
  const float inv = fac0 / sqrtf(ss);

  ushort4 o;
  o.x = f2bf(v.x * inv); o.y = f2bf(v.y * inv);
  o.z = f2bf(v.z * inv); o.w = f2bf(v.w * inv);
  ((ushort4*)(wsu + (size_t)m * GN * DDIM + (size_t)(g * 8 + r) * DDIM))[c4] = o;

  __shared__ float lds[8][DDIM];
  lds[r][c4 * 4 + 0] = bf2f(o.x);
  lds[r][c4 * 4 + 1] = bf2f(o.y);
  lds[r][c4 * 4 + 2] = bf2f(o.z);
  lds[r][c4 * 4 + 3] = bf2f(o.w);
  __syncthreads();
  if (t < DDIM) {
    float s = 0.f;
    #pragma unroll
    for (int j = 0; j < 8; ++j) s += lds[j][t];
    wf[GSUM + ((size_t)m * NGRP + g) * DDIM + t] = s;
  }
}

// FUSED single pass over S = A1 @ A2^T (log2 domain).
// grid 2048: idx = rowblk*16 + chunk. Block: 64 rows x 512 cols, 4 waves.
// A tile: s=0 fragments in VGPRs (loop-invariant), s=1..3 staged in LDS
// (XOR chunk swizzle, opaque offset keeps reads in-loop, no per-iter barrier).
// SWAPPED mfma: lane (li,q) reg r holds S[row0+16s+li][cb+q*4+r].
__global__ __launch_bounds__(256, 4) void gemm_stats(
    const ushort_t* __restrict__ wsu, const float* __restrict__ scp,
    float* __restrict__ wf) {
  const int idx = blockIdx.x;
  const int rowblk = idx >> 4;
  const int chunk = idx & 15;
  const int t = threadIdx.x;
  const int w = t >> 6;
  const int l = t & 63;
  const int li = l & 15;
  const int q = l >> 4;
  const float C = scp[0];
  const float nC2 = -C * LOG2E;

  const ushort_t* A = wsu;                       // f1 normalized * scale*log2e
  const ushort_t* B = wsu + (size_t)GN * DDIM;   // f2 normalized
  const int row0 = rowblk * 64;

  // s=0 A fragments held in registers (loop-invariant, 16 VGPRs)
  bf16x8 af0[4];
  #pragma unroll
  for (int ks = 0; ks < 4; ++ks)
    af0[ks] = *(const bf16x8*)(const void*)(A + (size_t)(row0 + li) * DDIM + ks * 32 + q * 8);

  // stage A tile: 64 rows x 128 cols bf16, chunk c8 stored at c8^(row&15)
  __shared__ ushort_t As[64 * 128];
  {
    const int arow = t >> 2;
    const int aq = t & 3;
    const ushort_t* Agp = A + (size_t)(row0 + arow) * DDIM + aq * 32;
    #pragma unroll
    for (int j = 0; j < 4; ++j) {
      const int swz = (aq * 4 + j) ^ (arow & 15);
      *(uint4*)(As + arow * 128 + swz * 8) = *(const uint4*)(const void*)(Agp + j * 8);
    }
  }
  __syncthreads();

  float esum[4] = {0.f, 0.f, 0.f, 0.f};
  float sbl[4]  = {0.f, 0.f, 0.f, 0.f};
  float sBr[4]  = {0.f, 0.f, 0.f, 0.f};
  float pu[4]   = {1.f, 1.f, 1.f, 1.f};
  float pbs[4]  = {1.f, 1.f, 1.f, 1.f};

  const ushort_t* Bp = B + ((size_t)(chunk * 512 + w * 16) + li) * DDIM + q * 8;
  const bool hasdia = (chunk == (row0 >> 9));
  const int idiag = (row0 & 511) >> 6;
  const f32x4 cinit = {nC2, nC2, nC2, nC2};

  #pragma unroll 1
  for (int i = 0; i < 8; ++i) {
    const ushort_t* Bi = Bp + (size_t)i * (64 * DDIM);
    bf16x8 bc[4];
    #pragma unroll
    for (int ks = 0; ks < 4; ++ks)
      bc[ks] = *(const bf16x8*)(const void*)(Bi + ks * 32);

    f32x4 acc[4];
    #pragma unroll
    for (int s = 0; s < 4; ++s) acc[s] = cinit;
    #pragma unroll
    for (int ks = 0; ks < 4; ++ks) {
      int co = (((ks * 4 + q) ^ li) * 8);
      asm volatile("" : "+v"(co));   // opaque: keeps As reads inside the loop
      bf16x8 a1 = *(const bf16x8*)(As + (16 + li) * 128 + co);
      bf16x8 a2 = *(const bf16x8*)(As + (32 + li) * 128 + co);
      bf16x8 a3 = *(const bf16x8*)(As + (48 + li) * 128 + co);
      acc[0] = __builtin_amdgcn_mfma_f32_16x16x32_bf16(bc[ks], af0[ks], acc[0], 0, 0, 0);
      acc[1] = __builtin_amdgcn_mfma_f32_16x16x32_bf16(bc[ks], a1, acc[1], 0, 0, 0);
      acc[2] = __builtin_amdgcn_mfma_f32_16x16x32_bf16(bc[ks], a2, acc[2], 0, 0, 0);
      acc[3] = __builtin_amdgcn_mfma_f32_16x16x32_bf16(bc[ks], a3, acc[3], 0, 0, 0);
    }

    const bool dia = hasdia && (i == idiag);
    const int cb = chunk * 512 + i * 64 + w * 16;
    float lvcP = 1.f;
    float ecolp[4] = {0.f, 0.f, 0.f, 0.f};
    float prodc[4] = {1.f, 1.f, 1.f, 1.f};

    #pragma unroll
    for (int s = 0; s < 4; ++s) {
      float e[4];
      #pragma unroll
      for (int r = 0; r < 4; ++r) e[r] = EXP2F(acc[s][r]);
      float tt = (e[0] + e[1]) + (e[2] + e[3]);
      esum[s] += tt;
      float u = tt + __shfl_xor(tt, 16);       // 8-col block row-sum (all lanes)
      pu[s] *= u * 262144.f;                   // 2^18 guard

      // col octet sums (8-row sums per col), valid lanes li=7/15
      float o_[4];
      #pragma unroll
      for (int r = 0; r < 4; ++r) {
        o_[r] = dpp_shr4_add(dpp_shr2_add(dpp_shr1_add(e[r])));
        prodc[r] *= o_[r] * 16777216.f;        // 2^24 guard
        ecolp[r] += o_[r];
        if (dia && w == s && ((li == 7 && q < 2) || (li == 15 && q >= 2)))
          wf[DT + GN + cb + q * 4 + r] = o_[r];   // pass1 diag col sumexp
      }
      // 8x8 block sum from octet sums: in-lane col sum + q-pair combine
      float sr_ = (o_[0] + o_[1]) + (o_[2] + o_[3]);
      float bs = sr_ + __shfl_xor(sr_, 16);    // valid on li=7 (oct0), li=15 (oct1)
      lvcP *= bs * 65536.f;                    // 2^16 guard
      pbs[s] *= bs * 16384.f;                  // 2^14 guard

      if (dia && w == s) {
        if (((q >> 1) == (li >> 3)) && ((q & 1) == 0))
          wf[DT + row0 + 16 * w + li] = u;     // pass0 diag row sumexp
        if (l == 7)  wf[DU8 + rowblk * 8 + 2 * w]     = bs;
        if (l == 47) wf[DU8 + rowblk * 8 + 2 * w + 1] = bs;
      }
    }

    if ((i & 3) == 3) {                        // flush deferred row-side logs
      #pragma unroll
      for (int s = 0; s < 4; ++s) {
        sbl[s] += LOG2FAST(pu[s]) - 72.f;      // 4 iters x 2^18
        pu[s] = 1.f;
        sBr[s] += LOG2FAST(pbs[s]) - 56.f;     // 4 iters x 2^14
        pbs[s] = 1.f;
      }
    }

    // combine octets (l <-> l^8) via row_ror:8 DPP; store col partials
    float lc[4];
    #pragma unroll
    for (int r = 0; r < 4; ++r) {
      ecolp[r] = dpp_ror8_add(ecolp[r]);       // 64-row sum on lanes li=7/15
      lc[r] = LOG2FAST(prodc[r]) - 96.f;       // sum of 4 octet logs (2^24 x4)
      lc[r] = dpp_ror8_add(lc[r]);             // all 8 row-groups
    }
    float lvc = LOG2FAST(lvcP) - 64.f;         // sum of 4 bs logs (2^16 x4)
    lvc = dpp_ror8_add(lvc);
    if (li == 7) {
      #pragma unroll
      for (int r = 0; r < 4; ++r) {
        float2 st; st.x = ecolp[r]; st.y = lc[r];
        *(float2*)(wf + COLP + ((size_t)rowblk * GN + cb + q * 4 + r) * 2) = st;
      }
    }
    if (l == 7)  wf[GRP2P + (size_t)rowblk * NGRP + (cb >> 3)]     = lvc;
    if (l == 39) wf[GRP2P + (size_t)rowblk * NGRP + (cb >> 3) + 1] = lvc;
  }

  // row-side wave reduction over q (xor16 + xor32)
  #pragma unroll
  for (int s = 0; s < 4; ++s) {
    esum[s] += __shfl_xor(esum[s], 16); esum[s] += __shfl_xor(esum[s], 32);
    sbl[s]  += __shfl_xor(sbl[s], 16);  sbl[s]  += __shfl_xor(sbl[s], 32);
    sBr[s]  += __shfl_xor(sBr[s], 16);  sBr[s]  += __shfl_xor(sBr[s], 32);
  }

  __shared__ float redE[4][64], redL[4][64], redB[4][8];
  if (q == 0) {
    #pragma unroll
    for (int s = 0; s < 4; ++s) {
      redE[w][16 * s + li] = esum[s];
      redL[w][16 * s + li] = 0.5f * sbl[s];
    }
  }
  if (l == 7) {
    #pragma unroll
    for (int s = 0; s < 4; ++s) redB[w][2 * s] = 0.5f * sBr[s];
  }
  if (l == 15) {
    #pragma unroll
    for (int s = 0; s < 4; ++s) redB[w][2 * s + 1] = 0.5f * sBr[s];
  }
  __syncthreads();

  if (t < 64) {
    const float E = redE[0][t] + redE[1][t] + redE[2][t] + redE[3][t];
    const float L = redL[0][t] + redL[1][t] + redL[2][t] + redL[3][t];
    const size_t o = ROWST + ((size_t)(row0 + t) * NCH + chunk) * 2;
    wf[o + 0] = E; wf[o + 1] = L;
  }
  if (t < 8) {
    const float s4 = redB[0][t] + redB[1][t] + redB[2][t] + redB[3][t];
    wf[GRPB + (size_t)(rowblk * 8 + t) * NCH + chunk] = s4;
  }
}

// reduce pass1 partials over the 128 rowblocks; blocks 288+ do the csum work
__global__ __launch_bounds__(256) void colred_kernel(float* __restrict__ wf) {
  const int b = blockIdx.x;            // 0..351
  const int t = threadIdx.x;
  const int lane = t & 31;
  const int slice = t >> 5;            // 0..7
  __shared__ float red[8][32][2];
  if (b < 256) {
    const int c = b * 32 + lane;
    float e = 0.f, ls = 0.f;
    #pragma unroll 4
    for (int k = 0; k < 16; ++k) {
      const int rb = slice * 16 + k;
      float2 v = *(const float2*)(wf + COLP + ((size_t)rb * GN + c) * 2);
      e += v.x; ls += v.y;
    }
    red[slice][lane][0] = e; red[slice][lane][1] = ls;
    __syncthreads();
    if (slice == 0) {
      float E = 0.f, L = 0.f;
      #pragma unroll
      for (int s2 = 0; s2 < 8; ++s2) { E += red[s2][lane][0]; L += red[s2][lane][1]; }
      wf[FIN2 + c * 2] = E; wf[FIN2 + c * 2 + 1] = L;
    }
  } else if (b < 288) {
    const int cg = (b - 256) * 32 + lane;
    float s = 0.f;
    #pragma unroll 4
    for (int k = 0; k < 16; ++k) s += wf[GRP2P + (size_t)(slice * 16 + k) * NGRP + cg];
    red[slice][lane][0] = s;
    __syncthreads();
    if (slice == 0) {
      float S = 0.f;
      #pragma unroll
      for (int s2 = 0; s2 < 8; ++s2) S += red[s2][lane][0];
      wf[SB2 + cg] = S;
    }
  } else {
    // column-sum partials (formerly csum_kernel): b2 = m*32 + seg
    const int b2 = b - 288;
    const int m = b2 >> 5;
    const int seg = b2 & 31;
    if (t < DDIM) {
      const float* gp = wf + GSUM + ((size_t)m * NGRP + seg * 32) * DDIM + t;
      float s = 0.f;
      #pragma unroll 8
      for (int g = 0; g < 32; ++g) s += gp[(size_t)g * DDIM];
      wf[CSUMP + ((size_t)m * 32 + seg) * DDIM + t] = s;
    }
  }
}

__global__ __launch_bounds__(256) void loss_kernel(
    const float* __restrict__ wf, const ushort_t* __restrict__ wsu,
    const float* __restrict__ scp, float* __restrict__ partials) {
  const int b = blockIdx.x;          // 0..63
  const int pass = b >> 5;
  const int rbase = (b & 31) * 256;
  const int t = threadIdx.x;
  const int row = rbase + t;
  const int g = row >> 3;
  const float C = scp[0];
  const float eps = 0.1f;

  __shared__ float cs_l[DDIM];
  if (t < DDIM) {
    const float* cp = wf + CSUMP + ((size_t)(pass ^ 1) * 32) * DDIM + t;
    float s = 0.f;
    #pragma unroll 8
    for (int seg = 0; seg < 32; ++seg) s += cp[(size_t)seg * DDIM];
    cs_l[t] = s;
  }
  __syncthreads();

  float E, L;
  if (pass == 0) {
    const size_t ro = ROWST + ((size_t)row * NCH) * 2;
    E = 0.f; L = 0.f;
    #pragma unroll
    for (int ch = 0; ch < NCH; ++ch) {
      E += wf[ro + 2 * ch];
      L += wf[ro + 2 * ch + 1];
    }
  } else {
    E = wf[FIN2 + row * 2];
    L = wf[FIN2 + row * 2 + 1];
  }

  // raw row sum and diag-block raw sum via rank-1 dots
  const ushort_t* M = wsu + (size_t)pass * GN * DDIM + (size_t)row * DDIM;
  const float* gs = wf + GSUM + ((size_t)(pass ^ 1) * NGRP + g) * DDIM;
  float r2 = 0.f, p2 = 0.f;
  const uint4* Mv = (const uint4*)(const void*)M;
  #pragma unroll
  for (int c = 0; c < 8; ++c) {
    uint4 vv = Mv[c];
    unsigned uu[4] = {vv.x, vv.y, vv.z, vv.w};
    #pragma unroll
    for (int j = 0; j < 4; ++j) {
      float flo = bf2f(uu[j] & 0xffffu);
      float fhi = bf2f(uu[j] >> 16);
      const int k = c * 8 + j * 2;
      r2 += flo * cs_l[k];   r2 += fhi * cs_l[k + 1];
      p2 += flo * gs[k];     p2 += fhi * gs[k + 1];
    }
  }
  const float R = LN2 * r2;
  const float P = LN2 * p2;

  const float Td = wf[DT + (size_t)pass * GN + row];
  const float logE = __logf(E);
  const float row_lse = C + logE;

  // part_slice
  float acc = ((1.f - eps) * (row_lse - P) + (eps / 8192.f) * (row_lse - R)) * (1.f / 8192.f);
  // whole_slice
  const float dl = C + __logf(Td);
  const float l8 = 9.0099363f;       // log(8192 - 8)
  const float mx = fmaxf(dl, l8);
  const float pos_lse = mx + __logf(__expf(dl - mx) + __expf(l8 - mx));
  acc += ((1.f - eps) * (row_lse - pos_lse) + (eps / 1024.f) * (1024.f * logE - LN2 * L)) * (1.f / 8192.f);

  __shared__ float shE[256], shR[256], shP[256];
  shE[t] = E; shR[t] = R; shP[t] = P;
  __syncthreads();
  if (t < 32) {
    float Eg = 0.f, Rg = 0.f, Pg = 0.f;
    #pragma unroll
    for (int j = 0; j < 8; ++j) { Eg += shE[t * 8 + j]; Rg += shR[t * 8 + j]; Pg += shP[t * 8 + j]; }
    const int g2 = (rbase >> 3) + t;
    float SB;
    if (pass == 0) {
      SB = 0.f;
      #pragma unroll
      for (int ch = 0; ch < NCH; ++ch) SB += wf[GRPB + (size_t)g2 * NCH + ch];
    } else {
      SB = wf[SB2 + g2];
    }
    const float U = wf[DU8 + g2];
    const float logEg = __logf(Eg);
    const float grp_lse = C + logEg;
    // part_block
    acc += ((1.f - eps) * (grp_lse - Pg * (1.f / 64.f)) + eps * (grp_lse - Rg * (1.f / 65536.f))) * (1.f / 1024.f);
    // whole_block
    const float dbl = C + __logf(U);
    acc += ((1.f - eps) * (grp_lse - dbl) + (eps / 1024.f) * (1024.f * logEg - LN2 * SB)) * (1.f / 1024.f);
  }

  #pragma unroll
  for (int d = 1; d < 64; d <<= 1) acc += __shfl_xor(acc, d);
  __shared__ float sr[4];
  if ((t & 63) == 0) sr[t >> 6] = acc;
  __syncthreads();
  if (t == 0) partials[b] = sr[0] + sr[1] + sr[2] + sr[3];
}

__global__ __launch_bounds__(64) void final_kernel(
    const float* __restrict__ partials, float* __restrict__ out) {
  const int t = threadIdx.x;
  float v = partials[t];
  #pragma unroll
  for (int d = 1; d < 64; d <<= 1) v += __shfl_xor(v, d);
  if (t == 0) out[0] = 0.125f * v;
}

extern "C" void kernel_launch(void* const* d_in, const int* in_sizes, int n_in,
                              void* d_out, int out_size, void* d_ws, size_t ws_size,
                              hipStream_t stream) {
  const float* f1 = (const float*)d_in[0];
  const float* f2 = (const float*)d_in[1];
  const float* sc = (const float*)d_in[2];
  ushort_t* wsu = (ushort_t*)d_ws;
  float* wf = (float*)((char*)d_ws + (size_t)2 * GN * DDIM * sizeof(ushort_t));
  float* out = (float*)d_out;

  hipLaunchKernelGGL(normg_kernel, dim3(2048), dim3(256), 0, stream, f1, f2, sc, wsu, wf);
  hipLaunchKernelGGL(gemm_stats, dim3(2048), dim3(256), 0, stream, wsu, sc, wf);
  hipLaunchKernelGGL(colred_kernel, dim3(352), dim3(256), 0, stream, wf);
  hipLaunchKernelGGL(loss_kernel, dim3(64), dim3(256), 0, stream, wf, wsu, sc, wf + PART);
  hipLaunchKernelGGL(final_kernel, dim3(1), dim3(64), 0, stream, wf + PART, out);
}

// Round 18
// 64.601 us; speedup vs baseline: 1.1132x; 1.1132x over previous
//
#include <hip/hip_runtime.h>
#include <math.h>

typedef __attribute__((ext_vector_type(8))) short bf16x8;
typedef __attribute__((ext_vector_type(4))) float f32x4;
typedef unsigned short ushort_t;

#define GN 8192
#define NGRP 1024
#define DDIM 128
#define NCH 16
#define LOG2E 1.4426950408889634f
#define LN2 0.6931471805599453f

#if __has_builtin(__builtin_amdgcn_exp2f)
#define EXP2F(x) __builtin_amdgcn_exp2f(x)
#else
#define EXP2F(x) exp2f(x)
#endif
#if __has_builtin(__builtin_amdgcn_logf)
#define LOG2FAST(x) __builtin_amdgcn_logf(x)
#else
#define LOG2FAST(x) log2f(x)
#endif

// float offsets in wf (wf = ws + 4MB bf16 region)
#define ROWST 0                          // [8192][16][2] pass0 row partials (E, L)
#define GRPB  (ROWST + GN*NCH*2)         // [1024][16]    pass0 group sB partials
#define DT    (GRPB + NGRP*NCH)          // [2][8192]     diag-block row/col sumexp
#define DU8   (DT + 2*GN)                // [1024]        diag 8x8 block sumexp (shared)
#define GSUM  (DU8 + NGRP)               // [2][1024][128] per-group column sums
#define CSUMP (GSUM + 2*NGRP*DDIM)       // [2][32][128]  column-sum partials
#define COLP  (CSUMP + 2*32*DDIM)        // [128][8192][2] pass1 col partials (E, L)
#define GRP2P (COLP + 128*GN*2)          // [128][1024]   pass1 col-group sB partials
#define FIN2  (GRP2P + 128*NGRP)         // [8192][2]     reduced pass1 (E, L)
#define SB2   (FIN2 + GN*2)              // [1024]        reduced pass1 group sB

__device__ __forceinline__ ushort_t f2bf(float x) {
  unsigned u = __float_as_uint(x);
  unsigned r = (u + 0x7fffu + ((u >> 16) & 1u)) >> 16;
  return (ushort_t)r;
}
__device__ __forceinline__ float bf2f(unsigned h) {
  return __uint_as_float(h << 16);
}

// DPP helpers. row_shr chains: octet sums valid on lanes li=7 / li=15.
__device__ __forceinline__ float dpp_shr1_add(float v) {
  int s = __builtin_amdgcn_update_dpp(0, __float_as_int(v), 0x111, 0xF, 0xF, true);
  return v + __int_as_float(s);
}
__device__ __forceinline__ float dpp_shr2_add(float v) {
  int s = __builtin_amdgcn_update_dpp(0, __float_as_int(v), 0x112, 0xF, 0xF, true);
  return v + __int_as_float(s);
}
__device__ __forceinline__ float dpp_shr4_add(float v) {
  int s = __builtin_amdgcn_update_dpp(0, __float_as_int(v), 0x114, 0xF, 0xF, true);
  return v + __int_as_float(s);
}
// row_ror:8 = lane l <-> l^8 within each 16-lane row
__device__ __forceinline__ float dpp_ror8_add(float v) {
  int s = __builtin_amdgcn_update_dpp(0, __float_as_int(v), 0x128, 0xF, 0xF, true);
  return v + __int_as_float(s);
}

// One block per (matrix m, group g): normalize 8 rows, store bf16, emit
// per-group column sums of the bf16-rounded values. Block 0 zeroes out[0].
__global__ __launch_bounds__(256) void normg_kernel(
    const float* __restrict__ f1, const float* __restrict__ f2,
    const float* __restrict__ scp, ushort_t* __restrict__ wsu,
    float* __restrict__ wf, float* __restrict__ out) {
  const int b = blockIdx.x;            // m*1024 + g
  const int m = b >> 10;
  const int g = b & 1023;
  const int t = threadIdx.x;
  if (b == 0 && t == 0) out[0] = 0.f;  // init for loss_kernel atomics
  const int r = t >> 5;
  const int c4 = t & 31;
  const float* __restrict__ f = m ? f2 : f1;
  const float fac0 = m ? 1.0f : (scp[0] * LOG2E);

  const float4 v = ((const float4*)(f + ((size_t)(g * 8 + r)) * DDIM))[c4];
  float ss = v.x * v.x + v.y * v.y + v.z * v.z + v.w * v.w;
  #pragma unroll
  for (int d = 1; d < 32; d <<= 1) ss += __shfl_xor(ss, d);
  const float inv = fac0 / sqrtf(ss);

  ushort4 o;
  o.x = f2bf(v.x * inv); o.y = f2bf(v.y * inv);
  o.z = f2bf(v.z * inv); o.w = f2bf(v.w * inv);
  ((ushort4*)(wsu + (size_t)m * GN * DDIM + (size_t)(g * 8 + r) * DDIM))[c4] = o;

  __shared__ float lds[8][DDIM];
  lds[r][c4 * 4 + 0] = bf2f(o.x);
  lds[r][c4 * 4 + 1] = bf2f(o.y);
  lds[r][c4 * 4 + 2] = bf2f(o.z);
  lds[r][c4 * 4 + 3] = bf2f(o.w);
  __syncthreads();
  if (t < DDIM) {
    float s = 0.f;
    #pragma unroll
    for (int j = 0; j < 8; ++j) s += lds[j][t];
    wf[GSUM + ((size_t)m * NGRP + g) * DDIM + t] = s;
  }
}

// FUSED single pass over S = A1 @ A2^T (log2 domain).  [R12 best-measured]
// grid 2048: idx = rowblk*16 + chunk. Block: 64 rows x 512 cols, 4 waves.
// A tile staged in LDS (XOR chunk swizzle); opaque LDS offset, no per-iter
// barrier. SWAPPED mfma: lane (li,q) reg r holds S[row0+16s+li][cb+q*4+r].
__global__ __launch_bounds__(256, 4) void gemm_stats(
    const ushort_t* __restrict__ wsu, const float* __restrict__ scp,
    float* __restrict__ wf) {
  const int idx = blockIdx.x;
  const int rowblk = idx >> 4;
  const int chunk = idx & 15;
  const int t = threadIdx.x;
  const int w = t >> 6;
  const int l = t & 63;
  const int li = l & 15;
  const int q = l >> 4;
  const float C = scp[0];
  const float nC2 = -C * LOG2E;

  const ushort_t* A = wsu;                       // f1 normalized * scale*log2e
  const ushort_t* B = wsu + (size_t)GN * DDIM;   // f2 normalized
  const int row0 = rowblk * 64;

  // stage A tile: 64 rows x 128 cols bf16, chunk c8 stored at c8^(row&15)
  __shared__ ushort_t As[64 * 128];
  {
    const int arow = t >> 2;
    const int aq = t & 3;
    const ushort_t* Agp = A + (size_t)(row0 + arow) * DDIM + aq * 32;
    #pragma unroll
    for (int j = 0; j < 4; ++j) {
      const int swz = (aq * 4 + j) ^ (arow & 15);
      *(uint4*)(As + arow * 128 + swz * 8) = *(const uint4*)(const void*)(Agp + j * 8);
    }
  }
  __syncthreads();

  float esum[4] = {0.f, 0.f, 0.f, 0.f};
  float sbl[4]  = {0.f, 0.f, 0.f, 0.f};
  float sBr[4]  = {0.f, 0.f, 0.f, 0.f};

  const ushort_t* Bp = B + ((size_t)(chunk * 512 + w * 16) + li) * DDIM + q * 8;
  const bool hasdia = (chunk == (row0 >> 9));
  const int idiag = (row0 & 511) >> 6;
  const f32x4 cinit = {nC2, nC2, nC2, nC2};

  #pragma unroll 1
  for (int i = 0; i < 8; ++i) {
    const ushort_t* Bi = Bp + (size_t)i * (64 * DDIM);
    bf16x8 bc[4];
    #pragma unroll
    for (int ks = 0; ks < 4; ++ks)
      bc[ks] = *(const bf16x8*)(const void*)(Bi + ks * 32);

    f32x4 acc[4];
    #pragma unroll
    for (int s = 0; s < 4; ++s) acc[s] = cinit;
    #pragma unroll
    for (int ks = 0; ks < 4; ++ks) {
      int co = (((ks * 4 + q) ^ li) * 8);
      asm volatile("" : "+v"(co));   // opaque: keeps As reads inside the loop
      bf16x8 a0[4];
      #pragma unroll
      for (int s = 0; s < 4; ++s)
        a0[s] = *(const bf16x8*)(As + (16 * s + li) * 128 + co);
      #pragma unroll
      for (int s = 0; s < 4; ++s)
        acc[s] = __builtin_amdgcn_mfma_f32_16x16x32_bf16(bc[ks], a0[s], acc[s], 0, 0, 0);
    }

    const bool dia = hasdia && (i == idiag);
    const int cb = chunk * 512 + i * 64 + w * 16;
    float lvc = 0.f;
    float ecolp[4] = {0.f, 0.f, 0.f, 0.f};
    float prodc[4] = {1.f, 1.f, 1.f, 1.f};

    #pragma unroll
    for (int s = 0; s < 4; ++s) {
      float e[4];
      #pragma unroll
      for (int r = 0; r < 4; ++r) e[r] = EXP2F(acc[s][r]);
      float tt = (e[0] + e[1]) + (e[2] + e[3]);
      esum[s] += tt;
      float u = tt + __shfl_xor(tt, 16);       // 8-col block row-sum (all lanes)
      sbl[s] += LOG2FAST(u);
      // 8x8 block sums: shr chain over rows; valid lanes li=7 (oct0), li=15 (oct1)
      float bs = dpp_shr4_add(dpp_shr2_add(dpp_shr1_add(u)));
      float lg = LOG2FAST(bs);
      sBr[s] += lg;                             // pass0 group term (valid li 7/15)
      lvc += lg;                                // pass1 col-group term

      // col octet sums (8-row sums per col), valid lanes li=7/15
      #pragma unroll
      for (int r = 0; r < 4; ++r) {
        float o_ = dpp_shr4_add(dpp_shr2_add(dpp_shr1_add(e[r])));
        prodc[r] *= o_ * 16777216.f;           // 2^24 guard
        ecolp[r] += o_;
        if (dia && w == s && ((li == 7 && q < 2) || (li == 15 && q >= 2)))
          wf[DT + GN + cb + q * 4 + r] = o_;   // pass1 diag col sumexp
      }
      if (dia && w == s) {
        if (((q >> 1) == (li >> 3)) && ((q & 1) == 0))
          wf[DT + row0 + 16 * w + li] = u;     // pass0 diag row sumexp
        if (l == 7)  wf[DU8 + rowblk * 8 + 2 * w]     = bs;
        if (l == 47) wf[DU8 + rowblk * 8 + 2 * w + 1] = bs;
      }
    }

    // combine octets (l <-> l^8) via row_ror:8 DPP; store col partials
    float lc[4];
    #pragma unroll
    for (int r = 0; r < 4; ++r) {
      ecolp[r] = dpp_ror8_add(ecolp[r]);       // 64-row sum on lanes li=7/15
      lc[r] = LOG2FAST(prodc[r]) - 96.f;       // sum of 4 octet logs (2^24 x4)
      lc[r] = dpp_ror8_add(lc[r]);             // all 8 row-groups
    }
    lvc = dpp_ror8_add(lvc);
    if (li == 7) {
      #pragma unroll
      for (int r = 0; r < 4; ++r) {
        float2 st; st.x = ecolp[r]; st.y = lc[r];
        *(float2*)(wf + COLP + ((size_t)rowblk * GN + cb + q * 4 + r) * 2) = st;
      }
    }
    if (l == 7)  wf[GRP2P + (size_t)rowblk * NGRP + (cb >> 3)]     = lvc;
    if (l == 39) wf[GRP2P + (size_t)rowblk * NGRP + (cb >> 3) + 1] = lvc;
  }

  // row-side wave reduction over q (xor16 + xor32)
  #pragma unroll
  for (int s = 0; s < 4; ++s) {
    esum[s] += __shfl_xor(esum[s], 16); esum[s] += __shfl_xor(esum[s], 32);
    sbl[s]  += __shfl_xor(sbl[s], 16);  sbl[s]  += __shfl_xor(sbl[s], 32);
    sBr[s]  += __shfl_xor(sBr[s], 16);  sBr[s]  += __shfl_xor(sBr[s], 32);
  }

  __shared__ float redE[4][64], redL[4][64], redB[4][8];
  if (q == 0) {
    #pragma unroll
    for (int s = 0; s < 4; ++s) {
      redE[w][16 * s + li] = esum[s];
      redL[w][16 * s + li] = 0.5f * sbl[s];
    }
  }
  if (l == 7) {
    #pragma unroll
    for (int s = 0; s < 4; ++s) redB[w][2 * s] = 0.5f * sBr[s];
  }
  if (l == 15) {
    #pragma unroll
    for (int s = 0; s < 4; ++s) redB[w][2 * s + 1] = 0.5f * sBr[s];
  }
  __syncthreads();

  if (t < 64) {
    const float E = redE[0][t] + redE[1][t] + redE[2][t] + redE[3][t];
    const float L = redL[0][t] + redL[1][t] + redL[2][t] + redL[3][t];
    const size_t o = ROWST + ((size_t)(row0 + t) * NCH + chunk) * 2;
    wf[o + 0] = E; wf[o + 1] = L;
  }
  if (t < 8) {
    const float s4 = redB[0][t] + redB[1][t] + redB[2][t] + redB[3][t];
    wf[GRPB + (size_t)(rowblk * 8 + t) * NCH + chunk] = s4;
  }
}

// reduce pass1 partials over the 128 rowblocks; blocks 288+ do the csum work
__global__ __launch_bounds__(256) void colred_kernel(float* __restrict__ wf) {
  const int b = blockIdx.x;            // 0..351
  const int t = threadIdx.x;
  const int lane = t & 31;
  const int slice = t >> 5;            // 0..7
  __shared__ float red[8][32][2];
  if (b < 256) {
    const int c = b * 32 + lane;
    float e = 0.f, ls = 0.f;
    #pragma unroll 4
    for (int k = 0; k < 16; ++k) {
      const int rb = slice * 16 + k;
      float2 v = *(const float2*)(wf + COLP + ((size_t)rb * GN + c) * 2);
      e += v.x; ls += v.y;
    }
    red[slice][lane][0] = e; red[slice][lane][1] = ls;
    __syncthreads();
    if (slice == 0) {
      float E = 0.f, L = 0.f;
      #pragma unroll
      for (int s2 = 0; s2 < 8; ++s2) { E += red[s2][lane][0]; L += red[s2][lane][1]; }
      wf[FIN2 + c * 2] = E; wf[FIN2 + c * 2 + 1] = L;
    }
  } else if (b < 288) {
    const int cg = (b - 256) * 32 + lane;
    float s = 0.f;
    #pragma unroll 4
    for (int k = 0; k < 16; ++k) s += wf[GRP2P + (size_t)(slice * 16 + k) * NGRP + cg];
    red[slice][lane][0] = s;
    __syncthreads();
    if (slice == 0) {
      float S = 0.f;
      #pragma unroll
      for (int s2 = 0; s2 < 8; ++s2) S += red[s2][lane][0];
      wf[SB2 + cg] = S;
    }
  } else {
    // column-sum partials (formerly csum_kernel): b2 = m*32 + seg
    const int b2 = b - 288;
    const int m = b2 >> 5;
    const int seg = b2 & 31;
    if (t < DDIM) {
      const float* gp = wf + GSUM + ((size_t)m * NGRP + seg * 32) * DDIM + t;
      float s = 0.f;
      #pragma unroll 8
      for (int g = 0; g < 32; ++g) s += gp[(size_t)g * DDIM];
      wf[CSUMP + ((size_t)m * 32 + seg) * DDIM + t] = s;
    }
  }
}

__global__ __launch_bounds__(256) void loss_kernel(
    const float* __restrict__ wf, const ushort_t* __restrict__ wsu,
    const float* __restrict__ scp, float* __restrict__ out) {
  const int b = blockIdx.x;          // 0..63
  const int pass = b >> 5;
  const int rbase = (b & 31) * 256;
  const int t = threadIdx.x;
  const int row = rbase + t;
  const int g = row >> 3;
  const float C = scp[0];
  const float eps = 0.1f;

  __shared__ float cs_l[DDIM];
  if (t < DDIM) {
    const float* cp = wf + CSUMP + ((size_t)(pass ^ 1) * 32) * DDIM + t;
    float s = 0.f;
    #pragma unroll 8
    for (int seg = 0; seg < 32; ++seg) s += cp[(size_t)seg * DDIM];
    cs_l[t] = s;
  }
  __syncthreads();

  float E, L;
  if (pass == 0) {
    const size_t ro = ROWST + ((size_t)row * NCH) * 2;
    E = 0.f; L = 0.f;
    #pragma unroll
    for (int ch = 0; ch < NCH; ++ch) {
      E += wf[ro + 2 * ch];
      L += wf[ro + 2 * ch + 1];
    }
  } else {
    E = wf[FIN2 + row * 2];
    L = wf[FIN2 + row * 2 + 1];
  }

  // raw row sum and diag-block raw sum via rank-1 dots
  const ushort_t* M = wsu + (size_t)pass * GN * DDIM + (size_t)row * DDIM;
  const float* gs = wf + GSUM + ((size_t)(pass ^ 1) * NGRP + g) * DDIM;
  float r2 = 0.f, p2 = 0.f;
  const uint4* Mv = (const uint4*)(const void*)M;
  #pragma unroll
  for (int c = 0; c < 8; ++c) {
    uint4 vv = Mv[c];
    unsigned uu[4] = {vv.x, vv.y, vv.z, vv.w};
    #pragma unroll
    for (int j = 0; j < 4; ++j) {
      float flo = bf2f(uu[j] & 0xffffu);
      float fhi = bf2f(uu[j] >> 16);
      const int k = c * 8 + j * 2;
      r2 += flo * cs_l[k];   r2 += fhi * cs_l[k + 1];
      p2 += flo * gs[k];     p2 += fhi * gs[k + 1];
    }
  }
  const float R = LN2 * r2;
  const float P = LN2 * p2;

  const float Td = wf[DT + (size_t)pass * GN + row];
  const float logE = __logf(E);
  const float row_lse = C + logE;

  // part_slice
  float acc = ((1.f - eps) * (row_lse - P) + (eps / 8192.f) * (row_lse - R)) * (1.f / 8192.f);
  // whole_slice
  const float dl = C + __logf(Td);
  const float l8 = 9.0099363f;       // log(8192 - 8)
  const float mx = fmaxf(dl, l8);
  const float pos_lse = mx + __logf(__expf(dl - mx) + __expf(l8 - mx));
  acc += ((1.f - eps) * (row_lse - pos_lse) + (eps / 1024.f) * (1024.f * logE - LN2 * L)) * (1.f / 8192.f);

  __shared__ float shE[256], shR[256], shP[256];
  shE[t] = E; shR[t] = R; shP[t] = P;
  __syncthreads();
  if (t < 32) {
    float Eg = 0.f, Rg = 0.f, Pg = 0.f;
    #pragma unroll
    for (int j = 0; j < 8; ++j) { Eg += shE[t * 8 + j]; Rg += shR[t * 8 + j]; Pg += shP[t * 8 + j]; }
    const int g2 = (rbase >> 3) + t;
    float SB;
    if (pass == 0) {
      SB = 0.f;
      #pragma unroll
      for (int ch = 0; ch < NCH; ++ch) SB += wf[GRPB + (size_t)g2 * NCH + ch];
    } else {
      SB = wf[SB2 + g2];
    }
    const float U = wf[DU8 + g2];
    const float logEg = __logf(Eg);
    const float grp_lse = C + logEg;
    // part_block
    acc += ((1.f - eps) * (grp_lse - Pg * (1.f / 64.f)) + eps * (grp_lse - Rg * (1.f / 65536.f))) * (1.f / 1024.f);
    // whole_block
    const float dbl = C + __logf(U);
    acc += ((1.f - eps) * (grp_lse - dbl) + (eps / 1024.f) * (1024.f * logEg - LN2 * SB)) * (1.f / 1024.f);
  }

  #pragma unroll
  for (int d = 1; d < 64; d <<= 1) acc += __shfl_xor(acc, d);
  __shared__ float sr[4];
  if ((t & 63) == 0) sr[t >> 6] = acc;
  __syncthreads();
  if (t == 0) atomicAdd(out, 0.125f * (sr[0] + sr[1] + sr[2] + sr[3]));
}

extern "C" void kernel_launch(void* const* d_in, const int* in_sizes, int n_in,
                              void* d_out, int out_size, void* d_ws, size_t ws_size,
                              hipStream_t stream) {
  const float* f1 = (const float*)d_in[0];
  const float* f2 = (const float*)d_in[1];
  const float* sc = (const float*)d_in[2];
  ushort_t* wsu = (ushort_t*)d_ws;
  float* wf = (float*)((char*)d_ws + (size_t)2 * GN * DDIM * sizeof(ushort_t));
  float* out = (float*)d_out;

  hipLaunchKernelGGL(normg_kernel, dim3(2048), dim3(256), 0, stream, f1, f2, sc, wsu, wf, out);
  hipLaunchKernelGGL(gemm_stats, dim3(2048), dim3(256), 0, stream, wsu, sc, wf);
  hipLaunchKernelGGL(colred_kernel, dim3(352), dim3(256), 0, stream, wf);
  hipLaunchKernelGGL(loss_kernel, dim3(64), dim3(256), 0, stream, wf, wsu, sc, out);
}